// Round 1
// baseline (1682.270 us; speedup 1.0000x reference)
//
#include <hip/hip_runtime.h>

#define N_NODES 100000
#define IN_F    256
#define OUT_F   64
#define D_CH    4
#define N_EDGE  800000

// ---------------------------------------------------------------------------
// Kernel A: Wh[i][n][k] = (feature[n] @ W[i])[k] * norm[n]
// Register-tiled fp32 GEMM: 4 rows x 4 cols per thread, 64 rows per block.
// No LDS: W slabs (64KB/channel) and feature tiles are served from L1/L2.
// ---------------------------------------------------------------------------
__global__ __launch_bounds__(256) void gemm_kernel(
    const float* __restrict__ feature, const float* __restrict__ norm,
    const float* __restrict__ W, float* __restrict__ Wh)
{
    const int tid = threadIdx.x;
    const int tr = tid >> 4;          // 0..15
    const int tc = tid & 15;          // 0..15
    const int r0 = blockIdx.x * 64 + tr * 4;
    const int c0 = tc * 4;

    bool rv[4];
#pragma unroll
    for (int j = 0; j < 4; ++j) rv[j] = (r0 + j) < N_NODES;

    for (int i = 0; i < D_CH; ++i) {
        const float* __restrict__ Wi = W + (size_t)i * IN_F * OUT_F;
        float acc[4][4];
#pragma unroll
        for (int j = 0; j < 4; ++j)
#pragma unroll
            for (int l = 0; l < 4; ++l) acc[j][l] = 0.f;

        for (int k0 = 0; k0 < IN_F; k0 += 4) {
            float4 a[4];
#pragma unroll
            for (int j = 0; j < 4; ++j)
                a[j] = rv[j] ? *(const float4*)(feature + (size_t)(r0 + j) * IN_F + k0)
                             : make_float4(0.f, 0.f, 0.f, 0.f);
            float4 b[4];
#pragma unroll
            for (int kk = 0; kk < 4; ++kk)
                b[kk] = *(const float4*)(Wi + (size_t)(k0 + kk) * OUT_F + c0);

#pragma unroll
            for (int j = 0; j < 4; ++j) {
                const float av[4] = {a[j].x, a[j].y, a[j].z, a[j].w};
#pragma unroll
                for (int kk = 0; kk < 4; ++kk) {
                    acc[j][0] += av[kk] * b[kk].x;
                    acc[j][1] += av[kk] * b[kk].y;
                    acc[j][2] += av[kk] * b[kk].z;
                    acc[j][3] += av[kk] * b[kk].w;
                }
            }
        }

#pragma unroll
        for (int j = 0; j < 4; ++j) {
            if (!rv[j]) continue;
            const float nm = norm[r0 + j];
            float4 o = make_float4(acc[j][0] * nm, acc[j][1] * nm,
                                   acc[j][2] * nm, acc[j][3] * nm);
            *(float4*)(Wh + ((size_t)i * N_NODES + (r0 + j)) * OUT_F + c0) = o;
        }
    }
}

// ---------------------------------------------------------------------------
// Kernel B: p_src[i][n] = Wh[i][n] . att_w[:64], p_dst[i][n] = Wh[i][n] . att_w[64:]
// One 64-lane wave per (channel, node); shuffle-reduce.
// ---------------------------------------------------------------------------
__global__ __launch_bounds__(256) void pvec_kernel(
    const float* __restrict__ Wh, const float* __restrict__ att_w,
    float* __restrict__ p_src, float* __restrict__ p_dst)
{
    const int w    = threadIdx.x >> 6;
    const int lane = threadIdx.x & 63;
    const int g    = blockIdx.x * 4 + w;       // 0 .. 4N-1  (= i*N + n)

    const float wh = Wh[(size_t)g * OUT_F + lane];
    float ps = wh * att_w[lane];
    float pd = wh * att_w[OUT_F + lane];
#pragma unroll
    for (int off = 32; off > 0; off >>= 1) {
        ps += __shfl_down(ps, off, 64);
        pd += __shfl_down(pd, off, 64);
    }
    if (lane == 0) {
        p_src[g] = ps;
        p_dst[g] = pd;
    }
}

// ---------------------------------------------------------------------------
// Kernel C: per edge: w = exp(leaky_relu(p_src[s] + p_dst[d]))   (max-free:
// softmax is shift-invariant and logits are O(3.5), so exp cannot overflow).
// atomicAdd z[d] += w (lane 0); atomicAdd out[d][i*64+k] += w * Wh[i][s][k].
// One wave per edge; 64 coalesced f32 atomics.
// ---------------------------------------------------------------------------
__global__ __launch_bounds__(256) void edge_kernel(
    const float* __restrict__ Wh, const float* __restrict__ p_src,
    const float* __restrict__ p_dst, const int* __restrict__ src,
    const int* __restrict__ dst, float* __restrict__ z,
    float* __restrict__ out)
{
    const int w    = threadIdx.x >> 6;
    const int lane = threadIdx.x & 63;
    const int i    = blockIdx.y;
    const int e    = blockIdx.x * 4 + w;

    const int s = src[(size_t)i * N_EDGE + e];
    const int d = dst[(size_t)i * N_EDGE + e];

    float x = p_src[i * N_NODES + s] + p_dst[i * N_NODES + d];
    x = (x > 0.f) ? x : 0.2f * x;
    const float wgt = __expf(x);

    if (lane == 0) atomicAdd(&z[i * N_NODES + d], wgt);

    const float wh = Wh[((size_t)i * N_NODES + s) * OUT_F + lane];
    atomicAdd(&out[(size_t)d * (D_CH * OUT_F) + i * OUT_F + lane], wgt * wh);
}

// ---------------------------------------------------------------------------
// Kernel D: out[n][c] = relu(out[n][c] / z[c/64][n] * norm[n]); 0 for empty segs.
// One block per node.
// ---------------------------------------------------------------------------
__global__ __launch_bounds__(256) void final_kernel(
    const float* __restrict__ z, const float* __restrict__ norm,
    float* __restrict__ out)
{
    const int n = blockIdx.x;
    const int c = threadIdx.x;
    const int i = c >> 6;
    const size_t idx = (size_t)n * (D_CH * OUT_F) + c;

    const float zz = z[i * N_NODES + n];
    float v = out[idx];
    const float nm = norm[n];
    v = (zz > 0.f) ? (v / zz) * nm : 0.f;
    out[idx] = (v > 0.f) ? v : 0.f;
}

// ---------------------------------------------------------------------------
extern "C" void kernel_launch(void* const* d_in, const int* in_sizes, int n_in,
                              void* d_out, int out_size, void* d_ws, size_t ws_size,
                              hipStream_t stream)
{
    const float* feature = (const float*)d_in[0];
    const float* norm    = (const float*)d_in[1];
    const float* W       = (const float*)d_in[2];
    const float* att_w   = (const float*)d_in[3];
    const int*   src     = (const int*)d_in[4];
    const int*   dst     = (const int*)d_in[5];
    float* out = (float*)d_out;

    // Workspace layout (f32): Wh[4*N*64] | p_src[4N] | p_dst[4N] | z[4N]
    float* Wh    = (float*)d_ws;
    float* p_src = Wh + (size_t)D_CH * N_NODES * OUT_F;
    float* p_dst = p_src + (size_t)D_CH * N_NODES;
    float* z     = p_dst + (size_t)D_CH * N_NODES;

    // Zero accumulators each call (graph-capture-safe).
    hipMemsetAsync(out, 0, (size_t)out_size * sizeof(float), stream);
    hipMemsetAsync(z, 0, (size_t)D_CH * N_NODES * sizeof(float), stream);

    gemm_kernel<<<dim3((N_NODES + 63) / 64), 256, 0, stream>>>(feature, norm, W, Wh);
    pvec_kernel<<<dim3((D_CH * N_NODES) / 4), 256, 0, stream>>>(Wh, att_w, p_src, p_dst);
    edge_kernel<<<dim3(N_EDGE / 4, D_CH), 256, 0, stream>>>(Wh, p_src, p_dst, src, dst, z, out);
    final_kernel<<<dim3(N_NODES), 256, 0, stream>>>(z, norm, out);
}

// Round 2
// 1268.818 us; speedup vs baseline: 1.3259x; 1.3259x over previous
//
#include <hip/hip_runtime.h>

#define N_NODES 100000
#define IN_F    256
#define OUT_F   64
#define D_CH    4
#define N_EDGE  800000
#define M_SEG   (D_CH * N_NODES)          // 400000 segments
#define SCAN_ITEMS 1024
#define SCAN_NB ((M_SEG + SCAN_ITEMS - 1) / SCAN_ITEMS)   // 391

// ---------------------------------------------------------------------------
// Kernel A: Wh[i][n][k] = (feature[n] @ W[i])[k] * norm[n]; fused epilogue
// computes p_src[i][n] = Wh[i][n].att_w[:64], p_dst = Wh[i][n].att_w[64:].
// Register-tiled fp32 GEMM: 4 rows x 4 cols per thread, 64 rows per block.
// ---------------------------------------------------------------------------
__global__ __launch_bounds__(256) void gemm_pvec_kernel(
    const float* __restrict__ feature, const float* __restrict__ norm,
    const float* __restrict__ W, const float* __restrict__ att_w,
    float* __restrict__ Wh, float* __restrict__ p_src, float* __restrict__ p_dst)
{
    const int tid = threadIdx.x;
    const int tr = tid >> 4;          // 0..15
    const int tc = tid & 15;          // 0..15
    const int r0 = blockIdx.x * 64 + tr * 4;
    const int c0 = tc * 4;

    bool rv[4];
#pragma unroll
    for (int j = 0; j < 4; ++j) rv[j] = (r0 + j) < N_NODES;

    const float4 asrc = *(const float4*)(att_w + c0);
    const float4 adst = *(const float4*)(att_w + OUT_F + c0);

    for (int i = 0; i < D_CH; ++i) {
        const float* __restrict__ Wi = W + (size_t)i * IN_F * OUT_F;
        float acc[4][4];
#pragma unroll
        for (int j = 0; j < 4; ++j)
#pragma unroll
            for (int l = 0; l < 4; ++l) acc[j][l] = 0.f;

        for (int k0 = 0; k0 < IN_F; k0 += 4) {
            float4 a[4];
#pragma unroll
            for (int j = 0; j < 4; ++j)
                a[j] = rv[j] ? *(const float4*)(feature + (size_t)(r0 + j) * IN_F + k0)
                             : make_float4(0.f, 0.f, 0.f, 0.f);
            float4 b[4];
#pragma unroll
            for (int kk = 0; kk < 4; ++kk)
                b[kk] = *(const float4*)(Wi + (size_t)(k0 + kk) * OUT_F + c0);

#pragma unroll
            for (int j = 0; j < 4; ++j) {
                const float av[4] = {a[j].x, a[j].y, a[j].z, a[j].w};
#pragma unroll
                for (int kk = 0; kk < 4; ++kk) {
                    acc[j][0] += av[kk] * b[kk].x;
                    acc[j][1] += av[kk] * b[kk].y;
                    acc[j][2] += av[kk] * b[kk].z;
                    acc[j][3] += av[kk] * b[kk].w;
                }
            }
        }

        float ps[4], pd[4];
#pragma unroll
        for (int j = 0; j < 4; ++j) {
            const float nm = rv[j] ? norm[r0 + j] : 0.f;
            float w0 = acc[j][0] * nm, w1 = acc[j][1] * nm;
            float w2 = acc[j][2] * nm, w3 = acc[j][3] * nm;
            if (rv[j]) {
                *(float4*)(Wh + ((size_t)i * N_NODES + (r0 + j)) * OUT_F + c0) =
                    make_float4(w0, w1, w2, w3);
            }
            ps[j] = w0 * asrc.x + w1 * asrc.y + w2 * asrc.z + w3 * asrc.w;
            pd[j] = w0 * adst.x + w1 * adst.y + w2 * adst.z + w3 * adst.w;
        }
        // reduce across the 16 tc-lanes (low 4 bits of lane id)
#pragma unroll
        for (int j = 0; j < 4; ++j) {
            float s1 = ps[j], s2 = pd[j];
#pragma unroll
            for (int off = 1; off < 16; off <<= 1) {
                s1 += __shfl_xor(s1, off, 64);
                s2 += __shfl_xor(s2, off, 64);
            }
            if (tc == 0 && rv[j]) {
                p_src[i * N_NODES + r0 + j] = s1;
                p_dst[i * N_NODES + r0 + j] = s2;
            }
        }
    }
}

// ---------------------------------------------------------------------------
// CSR build: histogram -> 3-kernel exclusive scan -> scatter (src, weight)
// ---------------------------------------------------------------------------
__global__ __launch_bounds__(256) void hist_kernel(
    const int* __restrict__ dst, int* __restrict__ counts)
{
    const int e = blockIdx.x * 256 + threadIdx.x;
    const int i = blockIdx.y;
    const int d = dst[(size_t)i * N_EDGE + e];
    atomicAdd(&counts[i * N_NODES + d], 1);
}

__global__ __launch_bounds__(256) void scan_reduce_kernel(
    const int* __restrict__ counts, int* __restrict__ bsum)
{
    __shared__ int lds[256];
    const int tid = threadIdx.x;
    const int base = blockIdx.x * SCAN_ITEMS + tid * 4;
    int s = 0;
#pragma unroll
    for (int k = 0; k < 4; ++k) {
        const int idx = base + k;
        if (idx < M_SEG) s += counts[idx];
    }
    lds[tid] = s;
    __syncthreads();
    for (int off = 128; off > 0; off >>= 1) {
        if (tid < off) lds[tid] += lds[tid + off];
        __syncthreads();
    }
    if (tid == 0) bsum[blockIdx.x] = lds[0];
}

__global__ __launch_bounds__(512) void scan_mid_kernel(
    const int* __restrict__ bsum, int* __restrict__ bscan, int* __restrict__ offs)
{
    __shared__ int lds[512];
    const int tid = threadIdx.x;
    const int v = (tid < SCAN_NB) ? bsum[tid] : 0;
    lds[tid] = v;
    __syncthreads();
    for (int off = 1; off < 512; off <<= 1) {
        int t = 0;
        if (tid >= off) t = lds[tid - off];
        __syncthreads();
        if (tid >= off) lds[tid] += t;
        __syncthreads();
    }
    if (tid < SCAN_NB) bscan[tid] = lds[tid] - v;   // exclusive
    if (tid == 511) offs[M_SEG] = lds[511];          // total (= D*E)
}

__global__ __launch_bounds__(256) void scan_final_kernel(
    const int* __restrict__ counts, const int* __restrict__ bscan,
    int* __restrict__ offs)
{
    __shared__ int lds[256];
    const int tid = threadIdx.x;
    const int base = blockIdx.x * SCAN_ITEMS + tid * 4;
    int c[4];
    int s = 0;
#pragma unroll
    for (int k = 0; k < 4; ++k) {
        const int idx = base + k;
        c[k] = (idx < M_SEG) ? counts[idx] : 0;
        s += c[k];
    }
    lds[tid] = s;
    __syncthreads();
    for (int off = 1; off < 256; off <<= 1) {
        int t = 0;
        if (tid >= off) t = lds[tid - off];
        __syncthreads();
        if (tid >= off) lds[tid] += t;
        __syncthreads();
    }
    int run = bscan[blockIdx.x] + lds[tid] - s;   // exclusive within grid
#pragma unroll
    for (int k = 0; k < 4; ++k) {
        const int idx = base + k;
        if (idx < M_SEG) offs[idx] = run;
        run += c[k];
    }
}

__global__ __launch_bounds__(256) void scatter_kernel(
    const int* __restrict__ src, const int* __restrict__ dst,
    const float* __restrict__ p_src, const float* __restrict__ p_dst,
    const int* __restrict__ offs, int* __restrict__ cursor,
    int* __restrict__ ssrc, float* __restrict__ swgt)
{
    const int e = blockIdx.x * 256 + threadIdx.x;
    const int i = blockIdx.y;
    const int s = src[(size_t)i * N_EDGE + e];
    const int d = dst[(size_t)i * N_EDGE + e];
    float x = p_src[i * N_NODES + s] + p_dst[i * N_NODES + d];
    x = (x > 0.f) ? x : 0.2f * x;
    const float w = __expf(x);   // max-free softmax: logits are O(4), no overflow
    const int pos = offs[i * N_NODES + d] + atomicAdd(&cursor[i * N_NODES + d], 1);
    ssrc[pos] = s;
    swgt[pos] = w;
}

// ---------------------------------------------------------------------------
// Aggregate: one wave per (channel, node). Registers accumulate 64 outputs +
// z; single coalesced store with the /z * norm + relu epilogue fused.
// ---------------------------------------------------------------------------
__global__ __launch_bounds__(256) void agg_kernel(
    const int* __restrict__ offs, const int* __restrict__ ssrc,
    const float* __restrict__ swgt, const float* __restrict__ Wh,
    const float* __restrict__ norm, float* __restrict__ out)
{
    const int wv   = threadIdx.x >> 6;
    const int lane = threadIdx.x & 63;
    const int gw   = blockIdx.x * 4 + wv;        // 0 .. M_SEG-1
    const int i    = gw / N_NODES;
    const int n    = gw - i * N_NODES;

    const int beg = offs[gw];
    const int end = offs[gw + 1];
    const float* __restrict__ whb = Wh + ((size_t)i * N_NODES) * OUT_F + lane;

    float acc0 = 0.f, acc1 = 0.f, z = 0.f;
    int e = beg;
    for (; e + 1 < end; e += 2) {
        const int s0 = ssrc[e], s1 = ssrc[e + 1];
        const float w0 = swgt[e], w1 = swgt[e + 1];
        acc0 += w0 * whb[(size_t)s0 * OUT_F];
        acc1 += w1 * whb[(size_t)s1 * OUT_F];
        z += w0 + w1;
    }
    if (e < end) {
        const int s0 = ssrc[e];
        const float w0 = swgt[e];
        acc0 += w0 * whb[(size_t)s0 * OUT_F];
        z += w0;
    }
    float v = acc0 + acc1;
    v = (z > 0.f) ? (v / z) * norm[n] : 0.f;
    out[(size_t)n * (D_CH * OUT_F) + i * OUT_F + lane] = (v > 0.f) ? v : 0.f;
}

// ---------------------------------------------------------------------------
// Fallback path (small ws): R1 atomic edge kernel + finalize
// ---------------------------------------------------------------------------
__global__ __launch_bounds__(256) void edge_kernel(
    const float* __restrict__ Wh, const float* __restrict__ p_src,
    const float* __restrict__ p_dst, const int* __restrict__ src,
    const int* __restrict__ dst, float* __restrict__ z,
    float* __restrict__ out)
{
    const int w    = threadIdx.x >> 6;
    const int lane = threadIdx.x & 63;
    const int i    = blockIdx.y;
    const int e    = blockIdx.x * 4 + w;

    const int s = src[(size_t)i * N_EDGE + e];
    const int d = dst[(size_t)i * N_EDGE + e];

    float x = p_src[i * N_NODES + s] + p_dst[i * N_NODES + d];
    x = (x > 0.f) ? x : 0.2f * x;
    const float wgt = __expf(x);
    if (lane == 0) atomicAdd(&z[i * N_NODES + d], wgt);
    const float wh = Wh[((size_t)i * N_NODES + s) * OUT_F + lane];
    atomicAdd(&out[(size_t)d * (D_CH * OUT_F) + i * OUT_F + lane], wgt * wh);
}

__global__ __launch_bounds__(256) void final_kernel(
    const float* __restrict__ z, const float* __restrict__ norm,
    float* __restrict__ out)
{
    const int n = blockIdx.x;
    const int c = threadIdx.x;
    const int i = c >> 6;
    const size_t idx = (size_t)n * (D_CH * OUT_F) + c;
    const float zz = z[i * N_NODES + n];
    float v = out[idx];
    const float nm = norm[n];
    v = (zz > 0.f) ? (v / zz) * nm : 0.f;
    out[idx] = (v > 0.f) ? v : 0.f;
}

// ---------------------------------------------------------------------------
extern "C" void kernel_launch(void* const* d_in, const int* in_sizes, int n_in,
                              void* d_out, int out_size, void* d_ws, size_t ws_size,
                              hipStream_t stream)
{
    const float* feature = (const float*)d_in[0];
    const float* norm    = (const float*)d_in[1];
    const float* W       = (const float*)d_in[2];
    const float* att_w   = (const float*)d_in[3];
    const int*   src     = (const int*)d_in[4];
    const int*   dst     = (const int*)d_in[5];
    float* out = (float*)d_out;

    // Workspace layout (CSR path):
    // Wh[25.6M f] | p_src[400K f] | p_dst[400K f] | offs[400004 i] |
    // counts[400K i] | bsum[512 i] | bscan[512 i] | ssrc[3.2M i] | swgt[3.2M f]
    float* Wh    = (float*)d_ws;
    float* p_src = Wh + (size_t)D_CH * N_NODES * OUT_F;
    float* p_dst = p_src + M_SEG;
    int*   offs   = (int*)(p_dst + M_SEG);
    int*   counts = offs + (M_SEG + 4);
    int*   bsum   = counts + M_SEG;
    int*   bscan  = bsum + 512;
    int*   ssrc   = bscan + 512;
    float* swgt   = (float*)(ssrc + (size_t)D_CH * N_EDGE);

    const size_t need_csr =
        ((size_t)D_CH * N_NODES * OUT_F + 2 * M_SEG) * 4 +      // Wh + p
        ((size_t)M_SEG + 4 + M_SEG + 1024) * 4 +                // offs + counts + bsums
        (size_t)D_CH * N_EDGE * 8;                              // ssrc + swgt

    gemm_pvec_kernel<<<dim3((N_NODES + 63) / 64), 256, 0, stream>>>(
        feature, norm, W, att_w, Wh, p_src, p_dst);

    if (ws_size >= need_csr) {
        hipMemsetAsync(counts, 0, (size_t)M_SEG * sizeof(int), stream);
        hist_kernel<<<dim3(N_EDGE / 256, D_CH), 256, 0, stream>>>(dst, counts);
        scan_reduce_kernel<<<dim3(SCAN_NB), 256, 0, stream>>>(counts, bsum);
        scan_mid_kernel<<<dim3(1), 512, 0, stream>>>(bsum, bscan, offs);
        scan_final_kernel<<<dim3(SCAN_NB), 256, 0, stream>>>(counts, bscan, offs);
        hipMemsetAsync(counts, 0, (size_t)M_SEG * sizeof(int), stream);  // cursor
        scatter_kernel<<<dim3(N_EDGE / 256, D_CH), 256, 0, stream>>>(
            src, dst, p_src, p_dst, offs, counts, ssrc, swgt);
        agg_kernel<<<dim3(M_SEG / 4), 256, 0, stream>>>(
            offs, ssrc, swgt, Wh, norm, out);
    } else {
        // Fallback: atomic push aggregation (z aliases the offs slot)
        float* z = (float*)offs;
        hipMemsetAsync(out, 0, (size_t)out_size * sizeof(float), stream);
        hipMemsetAsync(z, 0, (size_t)M_SEG * sizeof(float), stream);
        edge_kernel<<<dim3(N_EDGE / 4, D_CH), 256, 0, stream>>>(
            Wh, p_src, p_dst, src, dst, z, out);
        final_kernel<<<dim3(N_NODES), 256, 0, stream>>>(z, norm, out);
    }
}

// Round 3
// 644.034 us; speedup vs baseline: 2.6121x; 1.9701x over previous
//
#include <hip/hip_runtime.h>

#define N_NODES 100000
#define IN_F    256
#define OUT_F   64
#define D_CH    4
#define N_EDGE  800000
#define M_SEG   (D_CH * N_NODES)          // 400000 segments
#define SCAN_ITEMS 1024
#define SCAN_NB ((M_SEG + SCAN_ITEMS - 1) / SCAN_ITEMS)   // 391

typedef __attribute__((ext_vector_type(8))) short short8;
typedef __attribute__((ext_vector_type(4))) float f32x4;

__device__ inline ushort f2bf(float f) {           // round-to-nearest-even
    union { float f; unsigned u; } v; v.f = f;
    unsigned b = v.u + 0x7FFFu + ((v.u >> 16) & 1u);
    return (ushort)(b >> 16);
}
__device__ inline float bf2f(ushort u) {
    union { unsigned u; float f; } v; v.u = ((unsigned)u) << 16;
    return v.f;
}

// ---------------------------------------------------------------------------
// One-time: repack W (f32) into per-lane bf16 MFMA B-fragments.
// Fragment (i, ks, nt): lane l, elem j holds W[i][ks*32 + (l>>4)*8 + j][nt*16 + (l&15)]
// ---------------------------------------------------------------------------
__global__ __launch_bounds__(256) void bpack_kernel(
    const float* __restrict__ W, ushort* __restrict__ Bpack)
{
    const int t = blockIdx.x * 256 + threadIdx.x;      // 0 .. 8191
    if (t >= D_CH * 8 * 4 * 64) return;
    const int l  = t & 63;
    const int nt = (t >> 6) & 3;
    const int ks = (t >> 8) & 7;
    const int i  = t >> 11;
    const int n  = nt * 16 + (l & 15);
    const int k0 = ks * 32 + (l >> 4) * 8;
    ushort v[8];
#pragma unroll
    for (int j = 0; j < 8; ++j)
        v[j] = f2bf(W[((size_t)i * IN_F + k0 + j) * OUT_F + n]);
#pragma unroll
    for (int j = 0; j < 8; ++j)
        Bpack[(size_t)t * 8 + j] = v[j];
}

// ---------------------------------------------------------------------------
// MFMA GEMM + fused pvec epilogue.
// Block = 4 waves, 16 rows/wave. A-frags (whole K=256) held in registers,
// reused across the 4 channels. Wh stored as bf16.
// C/D layout (HW-verified): col = lane&15, row = (lane>>4)*4 + reg.
// ---------------------------------------------------------------------------
__global__ __launch_bounds__(256) void gemm_mfma_kernel(
    const float* __restrict__ feature, const float* __restrict__ norm,
    const ushort* __restrict__ Bpack, const float* __restrict__ att_w,
    ushort* __restrict__ Wh_b, float* __restrict__ p_src, float* __restrict__ p_dst)
{
    const int wv   = threadIdx.x >> 6;
    const int lane = threadIdx.x & 63;
    const int kg   = lane >> 4;                 // 0..3
    const int cl   = lane & 15;                 // col within tile
    const int r0   = blockIdx.x * 64 + wv * 16;

    // ---- load A fragments for the full K=256 (8 frags of bf16x8) ----
    const int rowm   = r0 + cl;
    const int rclamp = (rowm < N_NODES) ? rowm : (N_NODES - 1);
    const float* __restrict__ arow = feature + (size_t)rclamp * IN_F + kg * 8;
    short8 afrag[8];
#pragma unroll
    for (int ks = 0; ks < 8; ++ks) {
        const f32x4 x = *(const f32x4*)(arow + ks * 32);
        const f32x4 y = *(const f32x4*)(arow + ks * 32 + 4);
        short8 a;
        a[0] = (short)f2bf(x[0]); a[1] = (short)f2bf(x[1]);
        a[2] = (short)f2bf(x[2]); a[3] = (short)f2bf(x[3]);
        a[4] = (short)f2bf(y[0]); a[5] = (short)f2bf(y[1]);
        a[6] = (short)f2bf(y[2]); a[7] = (short)f2bf(y[3]);
        afrag[ks] = a;
    }

    // per-lane attention weights for this lane's columns
    float pa[4], pb[4];
#pragma unroll
    for (int nt = 0; nt < 4; ++nt) {
        pa[nt] = att_w[nt * 16 + cl];
        pb[nt] = att_w[OUT_F + nt * 16 + cl];
    }
    // per-lane row norms (rows owned by this lane in C/D layout)
    float nm[4];
    bool  rvld[4];
#pragma unroll
    for (int r = 0; r < 4; ++r) {
        const int rr = r0 + kg * 4 + r;
        rvld[r] = rr < N_NODES;
        nm[r] = rvld[r] ? norm[rr] : 0.f;
    }

    const short8* __restrict__ bp = (const short8*)Bpack;

    for (int i = 0; i < D_CH; ++i) {
        f32x4 acc[4];
#pragma unroll
        for (int nt = 0; nt < 4; ++nt) acc[nt] = (f32x4){0.f, 0.f, 0.f, 0.f};

#pragma unroll
        for (int ks = 0; ks < 8; ++ks) {
#pragma unroll
            for (int nt = 0; nt < 4; ++nt) {
                const short8 bf = bp[((((i * 8) + ks) * 4 + nt) << 6) + lane];
                acc[nt] = __builtin_amdgcn_mfma_f32_16x16x32_bf16(
                    afrag[ks], bf, acc[nt], 0, 0, 0);
            }
        }

        // epilogue: ×norm, store bf16 Wh, accumulate p partials
        float ps[4] = {0.f, 0.f, 0.f, 0.f}, pd[4] = {0.f, 0.f, 0.f, 0.f};
#pragma unroll
        for (int nt = 0; nt < 4; ++nt) {
#pragma unroll
            for (int r = 0; r < 4; ++r) {
                const float v = acc[nt][r] * nm[r];
                const int rr = r0 + kg * 4 + r;
                if (rvld[r])
                    Wh_b[((size_t)i * N_NODES + rr) * OUT_F + nt * 16 + cl] = f2bf(v);
                ps[r] += v * pa[nt];
                pd[r] += v * pb[nt];
            }
        }
#pragma unroll
        for (int r = 0; r < 4; ++r) {
            float s1 = ps[r], s2 = pd[r];
#pragma unroll
            for (int off = 1; off < 16; off <<= 1) {
                s1 += __shfl_xor(s1, off, 64);
                s2 += __shfl_xor(s2, off, 64);
            }
            if (cl == 0 && rvld[r]) {
                const int rr = r0 + kg * 4 + r;
                p_src[i * N_NODES + rr] = s1;
                p_dst[i * N_NODES + rr] = s2;
            }
        }
    }
}

// ---------------------------------------------------------------------------
// CSR build: histogram -> 3-kernel exclusive scan -> scatter (src, weight)
// ---------------------------------------------------------------------------
__global__ __launch_bounds__(256) void hist_kernel(
    const int* __restrict__ dst, int* __restrict__ counts)
{
    const int e = blockIdx.x * 256 + threadIdx.x;
    const int i = blockIdx.y;
    const int d = dst[(size_t)i * N_EDGE + e];
    atomicAdd(&counts[i * N_NODES + d], 1);
}

__global__ __launch_bounds__(256) void scan_reduce_kernel(
    const int* __restrict__ counts, int* __restrict__ bsum)
{
    __shared__ int lds[256];
    const int tid = threadIdx.x;
    const int base = blockIdx.x * SCAN_ITEMS + tid * 4;
    int s = 0;
#pragma unroll
    for (int k = 0; k < 4; ++k) {
        const int idx = base + k;
        if (idx < M_SEG) s += counts[idx];
    }
    lds[tid] = s;
    __syncthreads();
    for (int off = 128; off > 0; off >>= 1) {
        if (tid < off) lds[tid] += lds[tid + off];
        __syncthreads();
    }
    if (tid == 0) bsum[blockIdx.x] = lds[0];
}

__global__ __launch_bounds__(512) void scan_mid_kernel(
    const int* __restrict__ bsum, int* __restrict__ bscan, int* __restrict__ offs)
{
    __shared__ int lds[512];
    const int tid = threadIdx.x;
    const int v = (tid < SCAN_NB) ? bsum[tid] : 0;
    lds[tid] = v;
    __syncthreads();
    for (int off = 1; off < 512; off <<= 1) {
        int t = 0;
        if (tid >= off) t = lds[tid - off];
        __syncthreads();
        if (tid >= off) lds[tid] += t;
        __syncthreads();
    }
    if (tid < SCAN_NB) bscan[tid] = lds[tid] - v;   // exclusive
    if (tid == 511) offs[M_SEG] = lds[511];
}

__global__ __launch_bounds__(256) void scan_final_kernel(
    const int* __restrict__ counts, const int* __restrict__ bscan,
    int* __restrict__ offs)
{
    __shared__ int lds[256];
    const int tid = threadIdx.x;
    const int base = blockIdx.x * SCAN_ITEMS + tid * 4;
    int c[4];
    int s = 0;
#pragma unroll
    for (int k = 0; k < 4; ++k) {
        const int idx = base + k;
        c[k] = (idx < M_SEG) ? counts[idx] : 0;
        s += c[k];
    }
    lds[tid] = s;
    __syncthreads();
    for (int off = 1; off < 256; off <<= 1) {
        int t = 0;
        if (tid >= off) t = lds[tid - off];
        __syncthreads();
        if (tid >= off) lds[tid] += t;
        __syncthreads();
    }
    int run = bscan[blockIdx.x] + lds[tid] - s;
#pragma unroll
    for (int k = 0; k < 4; ++k) {
        const int idx = base + k;
        if (idx < M_SEG) offs[idx] = run;
        run += c[k];
    }
}

__global__ __launch_bounds__(256) void scatter_kernel(
    const int* __restrict__ src, const int* __restrict__ dst,
    const float* __restrict__ p_src, const float* __restrict__ p_dst,
    const int* __restrict__ offs, int* __restrict__ cursor,
    int* __restrict__ ssrc, float* __restrict__ swgt)
{
    const int e = blockIdx.x * 256 + threadIdx.x;
    const int i = blockIdx.y;
    const int s = src[(size_t)i * N_EDGE + e];
    const int d = dst[(size_t)i * N_EDGE + e];
    float x = p_src[i * N_NODES + s] + p_dst[i * N_NODES + d];
    x = (x > 0.f) ? x : 0.2f * x;
    const float w = __expf(x);   // max-free softmax: logits O(4), no overflow
    const int pos = offs[i * N_NODES + d] + atomicAdd(&cursor[i * N_NODES + d], 1);
    ssrc[pos] = s;
    swgt[pos] = w;
}

// ---------------------------------------------------------------------------
// Aggregate: one wave per (channel, node); bf16 Wh gathers; fused epilogue.
// ---------------------------------------------------------------------------
__global__ __launch_bounds__(256) void agg_kernel(
    const int* __restrict__ offs, const int* __restrict__ ssrc,
    const float* __restrict__ swgt, const ushort* __restrict__ Wh_b,
    const float* __restrict__ norm, float* __restrict__ out)
{
    const int wv   = threadIdx.x >> 6;
    const int lane = threadIdx.x & 63;
    const int gw   = blockIdx.x * 4 + wv;        // 0 .. M_SEG-1
    const int i    = gw / N_NODES;
    const int n    = gw - i * N_NODES;

    const int beg = offs[gw];
    const int end = offs[gw + 1];
    const ushort* __restrict__ whb = Wh_b + (size_t)i * N_NODES * OUT_F + lane;

    float acc0 = 0.f, acc1 = 0.f, z = 0.f;
    int e = beg;
    for (; e + 1 < end; e += 2) {
        const int s0 = ssrc[e], s1 = ssrc[e + 1];
        const float w0 = swgt[e], w1 = swgt[e + 1];
        acc0 += w0 * bf2f(whb[(size_t)s0 * OUT_F]);
        acc1 += w1 * bf2f(whb[(size_t)s1 * OUT_F]);
        z += w0 + w1;
    }
    if (e < end) {
        const int s0 = ssrc[e];
        const float w0 = swgt[e];
        acc0 += w0 * bf2f(whb[(size_t)s0 * OUT_F]);
        z += w0;
    }
    float v = acc0 + acc1;
    v = (z > 0.f) ? (v / z) * norm[n] : 0.f;
    out[(size_t)n * (D_CH * OUT_F) + i * OUT_F + lane] = (v > 0.f) ? v : 0.f;
}

// ---------------------------------------------------------------------------
extern "C" void kernel_launch(void* const* d_in, const int* in_sizes, int n_in,
                              void* d_out, int out_size, void* d_ws, size_t ws_size,
                              hipStream_t stream)
{
    const float* feature = (const float*)d_in[0];
    const float* norm    = (const float*)d_in[1];
    const float* W       = (const float*)d_in[2];
    const float* att_w   = (const float*)d_in[3];
    const int*   src     = (const int*)d_in[4];
    const int*   dst     = (const int*)d_in[5];
    float* out = (float*)d_out;

    // Workspace layout:
    // Wh_b[25.6M u16] | p_src[400K f] | p_dst[400K f] | offs[400004 i] |
    // counts[400K i] | bsum[512 i] | bscan[512 i] | Bpack[65536 u16] |
    // ssrc[3.2M i] | swgt[3.2M f]          total ~= 83.5 MB
    ushort* Wh_b  = (ushort*)d_ws;
    float*  p_src = (float*)(Wh_b + (size_t)M_SEG * OUT_F);
    float*  p_dst = p_src + M_SEG;
    int*    offs   = (int*)(p_dst + M_SEG);
    int*    counts = offs + (M_SEG + 4);
    int*    bsum   = counts + M_SEG;
    int*    bscan  = bsum + 512;
    ushort* Bpack  = (ushort*)(bscan + 512);
    int*    ssrc   = (int*)(Bpack + 65536);
    float*  swgt   = (float*)(ssrc + (size_t)D_CH * N_EDGE);

    bpack_kernel<<<dim3(32), 256, 0, stream>>>(W, Bpack);
    gemm_mfma_kernel<<<dim3((N_NODES + 63) / 64), 256, 0, stream>>>(
        feature, norm, Bpack, att_w, Wh_b, p_src, p_dst);

    hipMemsetAsync(counts, 0, (size_t)M_SEG * sizeof(int), stream);
    hist_kernel<<<dim3(N_EDGE / 256, D_CH), 256, 0, stream>>>(dst, counts);
    scan_reduce_kernel<<<dim3(SCAN_NB), 256, 0, stream>>>(counts, bsum);
    scan_mid_kernel<<<dim3(1), 512, 0, stream>>>(bsum, bscan, offs);
    scan_final_kernel<<<dim3(SCAN_NB), 256, 0, stream>>>(counts, bscan, offs);
    hipMemsetAsync(counts, 0, (size_t)M_SEG * sizeof(int), stream);  // cursor
    scatter_kernel<<<dim3(N_EDGE / 256, D_CH), 256, 0, stream>>>(
        src, dst, p_src, p_dst, offs, counts, ssrc, swgt);
    agg_kernel<<<dim3(M_SEG / 4), 256, 0, stream>>>(
        offs, ssrc, swgt, Wh_b, norm, out);
}

// Round 4
// 536.634 us; speedup vs baseline: 3.1349x; 1.2001x over previous
//
#include <hip/hip_runtime.h>

#define N_NODES 100000
#define IN_F    256
#define OUT_F   64
#define D_CH    4
#define N_EDGE  800000
#define M_SEG   (D_CH * N_NODES)          // 400000 segments

typedef __attribute__((ext_vector_type(8))) short short8;
typedef __attribute__((ext_vector_type(4))) float f32x4;

__device__ inline ushort f2bf(float f) {           // round-to-nearest-even
    union { float f; unsigned u; } v; v.f = f;
    unsigned b = v.u + 0x7FFFu + ((v.u >> 16) & 1u);
    return (ushort)(b >> 16);
}
__device__ inline float bf2f(ushort u) {
    union { unsigned u; float f; } v; v.u = ((unsigned)u) << 16;
    return v.f;
}

// ---------------------------------------------------------------------------
// One-time: repack W (f32) into per-lane bf16 MFMA B-fragments.
// Fragment (i, ks, nt): lane l, elem j holds W[i][ks*32 + (l>>4)*8 + j][nt*16 + (l&15)]
// ---------------------------------------------------------------------------
__global__ __launch_bounds__(256) void bpack_kernel(
    const float* __restrict__ W, ushort* __restrict__ Bpack)
{
    const int t = blockIdx.x * 256 + threadIdx.x;      // 0 .. 8191
    if (t >= D_CH * 8 * 4 * 64) return;
    const int l  = t & 63;
    const int nt = (t >> 6) & 3;
    const int ks = (t >> 8) & 7;
    const int i  = t >> 11;
    const int n  = nt * 16 + (l & 15);
    const int k0 = ks * 32 + (l >> 4) * 8;
    ushort v[8];
#pragma unroll
    for (int j = 0; j < 8; ++j)
        v[j] = f2bf(W[((size_t)i * IN_F + k0 + j) * OUT_F + n]);
#pragma unroll
    for (int j = 0; j < 8; ++j)
        Bpack[(size_t)t * 8 + j] = v[j];
}

// ---------------------------------------------------------------------------
// MFMA GEMM + fused pvec epilogue.
// Block = 4 waves, 16 rows/wave. A-frags (whole K=256) held in registers,
// reused across the 4 channels. Wh stored as bf16.
// C/D layout (HW-verified): col = lane&15, row = (lane>>4)*4 + reg.
// ---------------------------------------------------------------------------
__global__ __launch_bounds__(256) void gemm_mfma_kernel(
    const float* __restrict__ feature, const float* __restrict__ norm,
    const ushort* __restrict__ Bpack, const float* __restrict__ att_w,
    ushort* __restrict__ Wh_b, float* __restrict__ p_src, float* __restrict__ p_dst)
{
    const int wv   = threadIdx.x >> 6;
    const int lane = threadIdx.x & 63;
    const int kg   = lane >> 4;                 // 0..3
    const int cl   = lane & 15;                 // col within tile
    const int r0   = blockIdx.x * 64 + wv * 16;

    // ---- load A fragments for the full K=256 (8 frags of bf16x8) ----
    const int rowm   = r0 + cl;
    const int rclamp = (rowm < N_NODES) ? rowm : (N_NODES - 1);
    const float* __restrict__ arow = feature + (size_t)rclamp * IN_F + kg * 8;
    short8 afrag[8];
#pragma unroll
    for (int ks = 0; ks < 8; ++ks) {
        const f32x4 x = *(const f32x4*)(arow + ks * 32);
        const f32x4 y = *(const f32x4*)(arow + ks * 32 + 4);
        short8 a;
        a[0] = (short)f2bf(x[0]); a[1] = (short)f2bf(x[1]);
        a[2] = (short)f2bf(x[2]); a[3] = (short)f2bf(x[3]);
        a[4] = (short)f2bf(y[0]); a[5] = (short)f2bf(y[1]);
        a[6] = (short)f2bf(y[2]); a[7] = (short)f2bf(y[3]);
        afrag[ks] = a;
    }

    // per-lane attention weights for this lane's columns
    float pa[4], pb[4];
#pragma unroll
    for (int nt = 0; nt < 4; ++nt) {
        pa[nt] = att_w[nt * 16 + cl];
        pb[nt] = att_w[OUT_F + nt * 16 + cl];
    }
    // per-lane row norms (rows owned by this lane in C/D layout)
    float nm[4];
    bool  rvld[4];
#pragma unroll
    for (int r = 0; r < 4; ++r) {
        const int rr = r0 + kg * 4 + r;
        rvld[r] = rr < N_NODES;
        nm[r] = rvld[r] ? norm[rr] : 0.f;
    }

    const short8* __restrict__ bp = (const short8*)Bpack;

    for (int i = 0; i < D_CH; ++i) {
        f32x4 acc[4];
#pragma unroll
        for (int nt = 0; nt < 4; ++nt) acc[nt] = (f32x4){0.f, 0.f, 0.f, 0.f};

#pragma unroll
        for (int ks = 0; ks < 8; ++ks) {
#pragma unroll
            for (int nt = 0; nt < 4; ++nt) {
                const short8 bf = bp[((((i * 8) + ks) * 4 + nt) << 6) + lane];
                acc[nt] = __builtin_amdgcn_mfma_f32_16x16x32_bf16(
                    afrag[ks], bf, acc[nt], 0, 0, 0);
            }
        }

        // epilogue: ×norm, store bf16 Wh, accumulate p partials
        float ps[4] = {0.f, 0.f, 0.f, 0.f}, pd[4] = {0.f, 0.f, 0.f, 0.f};
#pragma unroll
        for (int nt = 0; nt < 4; ++nt) {
#pragma unroll
            for (int r = 0; r < 4; ++r) {
                const float v = acc[nt][r] * nm[r];
                const int rr = r0 + kg * 4 + r;
                if (rvld[r])
                    Wh_b[((size_t)i * N_NODES + rr) * OUT_F + nt * 16 + cl] = f2bf(v);
                ps[r] += v * pa[nt];
                pd[r] += v * pb[nt];
            }
        }
#pragma unroll
        for (int r = 0; r < 4; ++r) {
            float s1 = ps[r], s2 = pd[r];
#pragma unroll
            for (int off = 1; off < 16; off <<= 1) {
                s1 += __shfl_xor(s1, off, 64);
                s2 += __shfl_xor(s2, off, 64);
            }
            if (cl == 0 && rvld[r]) {
                const int rr = r0 + kg * 4 + r;
                p_src[i * N_NODES + rr] = s1;
                p_dst[i * N_NODES + rr] = s2;
            }
        }
    }
}

// ---------------------------------------------------------------------------
// Linked-list build: next[i][e] = atomicExch(&head[i][dst], e).
// next writes are SEQUENTIAL (e-indexed); only head (1.6 MB, L2) is random.
// ---------------------------------------------------------------------------
__global__ __launch_bounds__(256) void build_kernel(
    const int* __restrict__ dst, int* __restrict__ head, int* __restrict__ next)
{
    const int e = blockIdx.x * 256 + threadIdx.x;
    const int i = blockIdx.y;
    const int d = dst[(size_t)i * N_EDGE + e];
    const int old = atomicExch(&head[i * N_NODES + d], e);
    next[(size_t)i * N_EDGE + e] = old;
}

// ---------------------------------------------------------------------------
// Aggregate via linked lists: each wave walks 4 chains concurrently
// (independent pointer-chases -> 4 outstanding hop-loads hide latency).
// Edge weight recomputed in-register: w = exp(leaky(p_src[s] + p_dst[n])),
// p_dst[n] is a per-chain scalar, p_src is 1.6 MB (cache-resident).
// Epilogue: /z * norm, relu, single coalesced store. No float atomics anywhere.
// ---------------------------------------------------------------------------
__global__ __launch_bounds__(256) void agg_ll_kernel(
    const int* __restrict__ head, const int* __restrict__ next,
    const int* __restrict__ src, const float* __restrict__ p_src,
    const float* __restrict__ p_dst, const ushort* __restrict__ Wh_b,
    const float* __restrict__ norm, float* __restrict__ out)
{
    const int wv   = threadIdx.x >> 6;
    const int lane = threadIdx.x & 63;
    const int g0   = (blockIdx.x * 4 + wv) * 4;     // first of 4 segments
    // N_NODES % 4 == 0 -> all 4 segments share one channel.
    const int i  = g0 / N_NODES;
    const int n0 = g0 - i * N_NODES;

    const int*    __restrict__ srcb  = src  + (size_t)i * N_EDGE;
    const int*    __restrict__ nxtb  = next + (size_t)i * N_EDGE;
    const float*  __restrict__ psb   = p_src + i * N_NODES;
    const ushort* __restrict__ whb   = Wh_b + (size_t)i * N_NODES * OUT_F + lane;

    int   e[4];
    float acc[4], z[4], pd[4];
#pragma unroll
    for (int c = 0; c < 4; ++c) {
        e[c]   = head[g0 + c];
        pd[c]  = p_dst[g0 + c];
        acc[c] = 0.f;
        z[c]   = 0.f;
    }

    while ((e[0] | e[1] | e[2] | e[3]) >= 0 ||
           e[0] >= 0 || e[1] >= 0 || e[2] >= 0 || e[3] >= 0) {
#pragma unroll
        for (int c = 0; c < 4; ++c) {
            if (e[c] >= 0) {
                const int s = srcb[e[c]];
                float x = psb[s] + pd[c];
                x = (x > 0.f) ? x : 0.2f * x;
                const float w = __expf(x);   // max-free softmax: logits O(4)
                acc[c] += w * bf2f(whb[(size_t)s * OUT_F]);
                z[c]   += w;
                e[c] = nxtb[e[c]];
            }
        }
        if (e[0] < 0 && e[1] < 0 && e[2] < 0 && e[3] < 0) break;
    }

#pragma unroll
    for (int c = 0; c < 4; ++c) {
        const int n = n0 + c;
        float v = (z[c] > 0.f) ? (acc[c] / z[c]) * norm[n] : 0.f;
        out[(size_t)n * (D_CH * OUT_F) + i * OUT_F + lane] = (v > 0.f) ? v : 0.f;
    }
}

// ---------------------------------------------------------------------------
extern "C" void kernel_launch(void* const* d_in, const int* in_sizes, int n_in,
                              void* d_out, int out_size, void* d_ws, size_t ws_size,
                              hipStream_t stream)
{
    const float* feature = (const float*)d_in[0];
    const float* norm    = (const float*)d_in[1];
    const float* W       = (const float*)d_in[2];
    const float* att_w   = (const float*)d_in[3];
    const int*   src     = (const int*)d_in[4];
    const int*   dst     = (const int*)d_in[5];
    float* out = (float*)d_out;

    // Workspace layout:
    // Wh_b[25.6M u16 = 51.2MB] | p_src[400K f] | p_dst[400K f] |
    // head[400K i] | next[3.2M i] | Bpack[65536 u16]     total ~= 69 MB
    ushort* Wh_b  = (ushort*)d_ws;
    float*  p_src = (float*)(Wh_b + (size_t)M_SEG * OUT_F);
    float*  p_dst = p_src + M_SEG;
    int*    head  = (int*)(p_dst + M_SEG);
    int*    next  = head + M_SEG;
    ushort* Bpack = (ushort*)(next + (size_t)D_CH * N_EDGE);

    bpack_kernel<<<dim3(32), 256, 0, stream>>>(W, Bpack);
    gemm_mfma_kernel<<<dim3((N_NODES + 63) / 64), 256, 0, stream>>>(
        feature, norm, Bpack, att_w, Wh_b, p_src, p_dst);

    hipMemsetAsync(head, 0xFF, (size_t)M_SEG * sizeof(int), stream);  // head = -1
    build_kernel<<<dim3(N_EDGE / 256, D_CH), 256, 0, stream>>>(dst, head, next);
    agg_ll_kernel<<<dim3(M_SEG / 16), 256, 0, stream>>>(
        head, next, src, p_src, p_dst, Wh_b, norm, out);
}